// Round 1
// baseline (621.060 us; speedup 1.0000x reference)
//
#include <hip/hip_runtime.h>

#define N_TOT   500000
#define M_Q     1024
#define QB      16
#define NSPLIT  16
#define ABLK    256
#define CAND_MAX 8192

static const unsigned OUT_ROWS  = 259u * (unsigned)N_TOT;   // 129,500,000
static const unsigned OUT_USAGE = OUT_ROWS;                 // usage region start
static const unsigned OUT_IDX   = OUT_ROWS + (unsigned)N_TOT; // 130,000,000

// ---------------- Kernel A: partial argmin of 0.5*|s|^2 - p.s over N-chunks --------
__global__ __launch_bounds__(ABLK) void k_argmin(
    const float* __restrict__ pts, const float* __restrict__ mpts,
    float* __restrict__ partKey, int* __restrict__ partIdx)
{
    const int qb = blockIdx.x;           // query tile
    const int ns = blockIdx.y;           // N split
    const int qbase = qb * QB;
    const int chunk = N_TOT / NSPLIT;    // 31250
    const int n0 = ns * chunk;
    const int n1 = n0 + chunk;

    __shared__ float qs[QB * 3];
    const int tid = threadIdx.x;
    if (tid < QB * 3) qs[tid] = pts[qbase * 3 + tid];
    __syncthreads();

    float qx[QB], qy[QB], qz[QB];
#pragma unroll
    for (int i = 0; i < QB; i++) { qx[i] = qs[3*i]; qy[i] = qs[3*i+1]; qz[i] = qs[3*i+2]; }

    float bk[QB]; int bi[QB];
#pragma unroll
    for (int i = 0; i < QB; i++) { bk[i] = INFINITY; bi[i] = 0x7fffffff; }

    for (int n = n0 + tid; n < n1; n += ABLK) {
        float x = mpts[3*n+0], y = mpts[3*n+1], z = mpts[3*n+2];
        float h = 0.5f * (x*x + y*y + z*z);
#pragma unroll
        for (int i = 0; i < QB; i++) {
            float key = h - x*qx[i] - y*qy[i] - z*qz[i];
            bool lt = key < bk[i];            // strict < + ascending n => first-min kept
            bk[i] = lt ? key : bk[i];
            bi[i] = lt ? n   : bi[i];
        }
    }

    // wave (64-lane) reduce with low-index tie-break
    const int lane = tid & 63;
    const int wv   = tid >> 6;
#pragma unroll
    for (int off = 32; off > 0; off >>= 1) {
#pragma unroll
        for (int i = 0; i < QB; i++) {
            float ok = __shfl_down(bk[i], off, 64);
            int   oi = __shfl_down(bi[i], off, 64);
            if (ok < bk[i] || (ok == bk[i] && oi < bi[i])) { bk[i] = ok; bi[i] = oi; }
        }
    }

    __shared__ float wk[ABLK/64][QB];
    __shared__ int   wi[ABLK/64][QB];
    if (lane == 0) {
#pragma unroll
        for (int i = 0; i < QB; i++) { wk[wv][i] = bk[i]; wi[wv][i] = bi[i]; }
    }
    __syncthreads();
    if (tid < QB) {
        float k = wk[0][tid]; int ix = wi[0][tid];
#pragma unroll
        for (int w = 1; w < ABLK/64; w++) {
            float ok = wk[w][tid]; int oi = wi[w][tid];
            if (ok < k || (ok == k && oi < ix)) { k = ok; ix = oi; }
        }
        partKey[(qbase + tid) * NSPLIT + ns] = k;
        partIdx[(qbase + tid) * NSPLIT + ns] = ix;
    }
}

// ---------------- Kernel B: eviction order + final idx (single block) --------------
__global__ __launch_bounds__(1024) void k_evict(
    const float* __restrict__ pts, const int* __restrict__ usage,
    const float* __restrict__ partKey, const int* __restrict__ partIdx,
    int* __restrict__ finalIdx, float* __restrict__ out)
{
    __shared__ int      hist[1024];
    __shared__ int      scan[1024];
    __shared__ unsigned keys[CAND_MAX];
    __shared__ int      mscan[1024];
    __shared__ int      s_cnt, s_V;
    const int t = threadIdx.x;

    // 1) reduce NSPLIT partials per query (chunks in ascending-n order: strict <)
    float bk = INFINITY; int bi = 0x7fffffff;
#pragma unroll
    for (int s = 0; s < NSPLIT; s++) {
        float k = partKey[t * NSPLIT + s];
        int   i = partIdx[t * NSPLIT + s];
        if (k < bk) { bk = k; bi = i; }
    }
    float px = pts[3*t], py = pts[3*t+1], pz = pts[3*t+2];
    float d2 = px*px + py*py + pz*pz + 2.0f * bk;
    const bool mask = d2 > 1e-6f;    // dist = sqrt(max(d2,1e-12)) > 1e-3  <=>  d2 > 1e-6

    // 2) usage histogram (values are in [0,1000))
    hist[t] = 0;
    if (t == 0) s_cnt = 0;
    __syncthreads();
    for (int n = t; n < N_TOT; n += 1024) {
        unsigned v = (unsigned)usage[n];
        if (v > 1023u) v = 1023u;
        atomicAdd(&hist[v], 1);
    }
    __syncthreads();

    // 3) inclusive scan of hist
    scan[t] = hist[t]; __syncthreads();
    for (int off = 1; off < 1024; off <<= 1) {
        int add = (t >= off) ? scan[t - off] : 0;
        __syncthreads();
        scan[t] += add;
        __syncthreads();
    }
    int cum  = scan[t] - hist[t];   // exclusive count(usage < t)
    int cumN = scan[t];             // inclusive count(usage <= t)
    if (cum < M_Q && cumN >= M_Q) s_V = t;   // unique crossing bin
    __syncthreads();
    const int V = s_V;

    // 4) collect candidate slots with usage <= V (unordered; sorted below)
    for (int n = t; n < N_TOT; n += 1024) {
        int u = usage[n];
        if (u <= V) {
            int p = atomicAdd(&s_cnt, 1);
            if (p < CAND_MAX) keys[p] = ((unsigned)u << 19) | (unsigned)n;  // n < 2^19
        }
    }
    __syncthreads();
    int C = s_cnt; if (C > CAND_MAX) C = CAND_MAX;
    for (int p = C + t; p < CAND_MAX; p += 1024) keys[p] = 0xFFFFFFFFu;
    __syncthreads();

    // 5) bitonic sort ascending -> (usage asc, index asc) == lax.top_k order
    for (int k = 2; k <= CAND_MAX; k <<= 1) {
        for (int j = k >> 1; j > 0; j >>= 1) {
#pragma unroll
            for (int i0 = 0; i0 < CAND_MAX / 1024; i0++) {
                int i = t + i0 * 1024;
                int ixj = i ^ j;
                if (ixj > i) {
                    unsigned a = keys[i], b = keys[ixj];
                    bool up = ((i & k) == 0);
                    if ((a > b) == up) { keys[i] = b; keys[ixj] = a; }
                }
            }
            __syncthreads();
        }
    }

    // 6) rank = cumsum(mask)-1 ; final idx
    mscan[t] = mask ? 1 : 0; __syncthreads();
    for (int off = 1; off < 1024; off <<= 1) {
        int add = (t >= off) ? mscan[t - off] : 0;
        __syncthreads();
        mscan[t] += add;
        __syncthreads();
    }
    int rank = mscan[t] - 1;
    int idx = mask ? (int)(keys[rank] & 0x7FFFFu) : bi;
    finalIdx[t] = idx;
    out[(size_t)OUT_IDX + (size_t)t] = (float)idx;
}

// ---------------- Kernel C: big copy (rows + usage-as-float) -----------------------
__global__ __launch_bounds__(256) void k_copy(
    const float* __restrict__ mpts, const float* __restrict__ mdesc,
    const int* __restrict__ usage, float* __restrict__ out)
{
    const unsigned TOTQ = (OUT_ROWS + (unsigned)N_TOT) / 4u;  // 32,500,000 float4s
    const unsigned stride = gridDim.x * blockDim.x;
    for (unsigned g = blockIdx.x * blockDim.x + threadIdx.x; g < TOTQ; g += stride) {
        unsigned e = g * 4u;
        float4 v;
        if (e < OUT_ROWS) {
            unsigned n = e / 259u;
            unsigned r = e - n * 259u;
            float tmp[4];
#pragma unroll
            for (int j = 0; j < 4; j++) {
                tmp[j] = (r < 3u) ? mpts[n * 3u + r] : mdesc[n * 256u + (r - 3u)];
                r++;
                if (r == 259u) { r = 0u; n++; }
            }
            v = make_float4(tmp[0], tmp[1], tmp[2], tmp[3]);
        } else {
            unsigned n = e - OUT_ROWS;
            v = make_float4((float)usage[n], (float)usage[n+1],
                            (float)usage[n+2], (float)usage[n+3]);
        }
        *reinterpret_cast<float4*>(out + e) = v;
    }
}

// ---------------- Kernel D: usage scatter-add ---------------------------------------
__global__ __launch_bounds__(1024) void k_usage_add(
    const int* __restrict__ finalIdx, float* __restrict__ out)
{
    int m = threadIdx.x;
    if (m < M_Q) atomicAdd(out + OUT_USAGE + finalIdx[m], 1.0f);
}

extern "C" void kernel_launch(void* const* d_in, const int* in_sizes, int n_in,
                              void* d_out, int out_size, void* d_ws, size_t ws_size,
                              hipStream_t stream)
{
    (void)in_sizes; (void)n_in; (void)out_size; (void)ws_size;
    const float* pts   = (const float*)d_in[0];
    // d_in[1] = descriptors: unused by the reference
    const float* mpts  = (const float*)d_in[2];
    const float* mdesc = (const float*)d_in[3];
    const int*   usage = (const int*)d_in[4];
    float* out = (float*)d_out;

    float* partKey  = (float*)d_ws;                                   // M*NSPLIT f32
    int*   partIdx  = (int*)((char*)d_ws + (size_t)M_Q * NSPLIT * 4); // M*NSPLIT i32
    int*   finalIdx = (int*)((char*)d_ws + (size_t)2 * M_Q * NSPLIT * 4);

    dim3 gA(M_Q / QB, NSPLIT);
    k_argmin<<<gA, ABLK, 0, stream>>>(pts, mpts, partKey, partIdx);
    k_evict<<<1, 1024, 0, stream>>>(pts, usage, partKey, partIdx, finalIdx, out);
    k_copy<<<2048, 256, 0, stream>>>(mpts, mdesc, usage, out);
    k_usage_add<<<1, 1024, 0, stream>>>(finalIdx, out);
}

// Round 2
// 437.093 us; speedup vs baseline: 1.4209x; 1.4209x over previous
//
#include <hip/hip_runtime.h>

#define N_TOT   500000
#define M_Q     1024
#define QB      16
#define NSPLIT  16
#define ABLK    256
#define CAND_MAX 8192

static const unsigned OUT_ROWS  = 259u * (unsigned)N_TOT;     // 129,500,000
static const unsigned OUT_USAGE = OUT_ROWS;                   // usage region start
static const unsigned OUT_IDX   = OUT_ROWS + (unsigned)N_TOT; // 130,000,000

// ---- ws layout (bytes) ----
// 0        partKey   M*NSPLIT f32   (65536)
// 65536    partIdx   M*NSPLIT i32   (65536)
// 131072   hist      1024 i32       (4096)
// 135168   V         1 i32
// 135172   cnt       1 i32
// 135176   keys      CAND_MAX u32   (32768)
#define WS_PARTKEY 0
#define WS_PARTIDX 65536
#define WS_HIST    131072
#define WS_V       135168
#define WS_CNT     135172
#define WS_KEYS    135176

// ---------------- Kernel A: partial argmin of 0.5*|s|^2 - p.s over N-chunks --------
__global__ __launch_bounds__(ABLK) void k_argmin(
    const float* __restrict__ pts, const float* __restrict__ mpts,
    float* __restrict__ partKey, int* __restrict__ partIdx)
{
    const int qb = blockIdx.x;
    const int ns = blockIdx.y;
    const int qbase = qb * QB;
    const int chunk = N_TOT / NSPLIT;    // 31250
    const int n0 = ns * chunk;
    const int n1 = n0 + chunk;

    __shared__ float qs[QB * 3];
    const int tid = threadIdx.x;
    if (tid < QB * 3) qs[tid] = pts[qbase * 3 + tid];
    __syncthreads();

    float qx[QB], qy[QB], qz[QB];
#pragma unroll
    for (int i = 0; i < QB; i++) { qx[i] = qs[3*i]; qy[i] = qs[3*i+1]; qz[i] = qs[3*i+2]; }

    float bk[QB]; int bi[QB];
#pragma unroll
    for (int i = 0; i < QB; i++) { bk[i] = INFINITY; bi[i] = 0x7fffffff; }

    for (int n = n0 + tid; n < n1; n += ABLK) {
        float x = mpts[3*n+0], y = mpts[3*n+1], z = mpts[3*n+2];
        float h = 0.5f * (x*x + y*y + z*z);
#pragma unroll
        for (int i = 0; i < QB; i++) {
            float key = h - x*qx[i] - y*qy[i] - z*qz[i];
            bool lt = key < bk[i];            // strict < + ascending n => first-min kept
            bk[i] = lt ? key : bk[i];
            bi[i] = lt ? n   : bi[i];
        }
    }

    const int lane = tid & 63;
    const int wv   = tid >> 6;
#pragma unroll
    for (int off = 32; off > 0; off >>= 1) {
#pragma unroll
        for (int i = 0; i < QB; i++) {
            float ok = __shfl_down(bk[i], off, 64);
            int   oi = __shfl_down(bi[i], off, 64);
            if (ok < bk[i] || (ok == bk[i] && oi < bi[i])) { bk[i] = ok; bi[i] = oi; }
        }
    }

    __shared__ float wk[ABLK/64][QB];
    __shared__ int   wi[ABLK/64][QB];
    if (lane == 0) {
#pragma unroll
        for (int i = 0; i < QB; i++) { wk[wv][i] = bk[i]; wi[wv][i] = bi[i]; }
    }
    __syncthreads();
    if (tid < QB) {
        float k = wk[0][tid]; int ix = wi[0][tid];
#pragma unroll
        for (int w = 1; w < ABLK/64; w++) {
            float ok = wk[w][tid]; int oi = wi[w][tid];
            if (ok < k || (ok == k && oi < ix)) { k = ok; ix = oi; }
        }
        partKey[(qbase + tid) * NSPLIT + ns] = k;
        partIdx[(qbase + tid) * NSPLIT + ns] = ix;
    }
}

// ---------------- zero ws state (poisoned 0xAA, never re-poisoned) -----------------
__global__ __launch_bounds__(1024) void k_zero(int* __restrict__ hist,
                                               int* __restrict__ cnt)
{
    hist[threadIdx.x] = 0;
    if (threadIdx.x == 0) *cnt = 0;
}

// ---------------- histogram of usage (values < 1024) -------------------------------
__global__ __launch_bounds__(1024) void k_hist(
    const int* __restrict__ usage, int* __restrict__ hist)
{
    __shared__ int lh[1024];
    const int t = threadIdx.x;
    lh[t] = 0;
    __syncthreads();
    const int stride = gridDim.x * 1024;
    for (int n = blockIdx.x * 1024 + t; n < N_TOT; n += stride) {
        unsigned v = (unsigned)usage[n];
        if (v > 1023u) v = 1023u;
        atomicAdd(&lh[v], 1);
    }
    __syncthreads();
    if (lh[t] != 0) atomicAdd(&hist[t], lh[t]);
}

// ---------------- scan hist, find cutoff bin V --------------------------------------
__global__ __launch_bounds__(1024) void k_scanV(
    const int* __restrict__ hist, int* __restrict__ Vout)
{
    __shared__ int scan[1024];
    const int t = threadIdx.x;
    int h = hist[t];
    scan[t] = h; __syncthreads();
    for (int off = 1; off < 1024; off <<= 1) {
        int add = (t >= off) ? scan[t - off] : 0;
        __syncthreads();
        scan[t] += add;
        __syncthreads();
    }
    int cum  = scan[t] - h;   // count(usage < t)
    int cumN = scan[t];       // count(usage <= t)
    if (cum < M_Q && cumN >= M_Q) *Vout = t;
}

// ---------------- collect candidate slots (usage <= V), unordered -------------------
__global__ __launch_bounds__(256) void k_collect(
    const int* __restrict__ usage, const int* __restrict__ Vp,
    int* __restrict__ cnt, unsigned* __restrict__ keys)
{
    const int V = *Vp;
    const int stride = gridDim.x * 256;
    for (int n = blockIdx.x * 256 + threadIdx.x; n < N_TOT; n += stride) {
        int u = usage[n];
        if (u <= V) {
            int p = atomicAdd(cnt, 1);
            if (p < CAND_MAX) keys[p] = ((unsigned)u << 19) | (unsigned)n;
        }
    }
}

// ---------------- Kernel C: big copy (rows + usage-as-float) -----------------------
__global__ __launch_bounds__(256) void k_copy(
    const float* __restrict__ mpts, const float* __restrict__ mdesc,
    const int* __restrict__ usage, float* __restrict__ out)
{
    const unsigned TOTQ = (OUT_ROWS + (unsigned)N_TOT) / 4u;  // 32,500,000 float4s
    const unsigned stride = gridDim.x * blockDim.x;
    for (unsigned g = blockIdx.x * blockDim.x + threadIdx.x; g < TOTQ; g += stride) {
        unsigned e = g * 4u;
        float4 v;
        if (e < OUT_ROWS) {
            unsigned n = e / 259u;
            unsigned r = e - n * 259u;
            float tmp[4];
#pragma unroll
            for (int j = 0; j < 4; j++) {
                tmp[j] = (r < 3u) ? mpts[n * 3u + r] : mdesc[n * 256u + (r - 3u)];
                r++;
                if (r == 259u) { r = 0u; n++; }
            }
            v = make_float4(tmp[0], tmp[1], tmp[2], tmp[3]);
        } else {
            unsigned n = e - OUT_ROWS;
            v = make_float4((float)usage[n], (float)usage[n+1],
                            (float)usage[n+2], (float)usage[n+3]);
        }
        *reinterpret_cast<float4*>(out + e) = v;
    }
}

// ---------------- final: sort candidates, rank, idx out, usage bump ----------------
__global__ __launch_bounds__(1024) void k_final(
    const float* __restrict__ pts,
    const float* __restrict__ partKey, const int* __restrict__ partIdx,
    const int* __restrict__ cntP, const unsigned* __restrict__ keysG,
    float* __restrict__ out)
{
    __shared__ unsigned keys[CAND_MAX];
    __shared__ int      mscan[1024];
    const int t = threadIdx.x;

    // 1) reduce NSPLIT partials per query (ascending-n chunk order: strict <)
    float bk = INFINITY; int bi = 0x7fffffff;
#pragma unroll
    for (int s = 0; s < NSPLIT; s++) {
        float k = partKey[t * NSPLIT + s];
        int   i = partIdx[t * NSPLIT + s];
        if (k < bk) { bk = k; bi = i; }
    }
    float px = pts[3*t], py = pts[3*t+1], pz = pts[3*t+2];
    float d2 = px*px + py*py + pz*pz + 2.0f * bk;
    const bool mask = d2 > 1e-6f;   // sqrt(max(d2,1e-12)) > 1e-3

    // 2) load candidates, pad to CAND_MAX
    int C = *cntP; if (C > CAND_MAX) C = CAND_MAX;
#pragma unroll
    for (int i0 = 0; i0 < CAND_MAX / 1024; i0++) {
        int p = t + i0 * 1024;
        keys[p] = (p < C) ? keysG[p] : 0xFFFFFFFFu;
    }
    __syncthreads();

    // 3) bitonic sort ascending -> (usage asc, index asc) == lax.top_k order
    for (int k = 2; k <= CAND_MAX; k <<= 1) {
        for (int j = k >> 1; j > 0; j >>= 1) {
#pragma unroll
            for (int i0 = 0; i0 < CAND_MAX / 1024; i0++) {
                int i = t + i0 * 1024;
                int ixj = i ^ j;
                if (ixj > i) {
                    unsigned a = keys[i], b = keys[ixj];
                    bool up = ((i & k) == 0);
                    if ((a > b) == up) { keys[i] = b; keys[ixj] = a; }
                }
            }
            __syncthreads();
        }
    }

    // 4) rank = cumsum(mask)-1 ; final idx; outputs
    mscan[t] = mask ? 1 : 0; __syncthreads();
    for (int off = 1; off < 1024; off <<= 1) {
        int add = (t >= off) ? mscan[t - off] : 0;
        __syncthreads();
        mscan[t] += add;
        __syncthreads();
    }
    int rank = mscan[t] - 1;
    int idx = mask ? (int)(keys[rank] & 0x7FFFFu) : bi;
    out[(size_t)OUT_IDX + (size_t)t] = (float)idx;
    atomicAdd(out + OUT_USAGE + idx, 1.0f);   // after k_copy wrote base usage
}

extern "C" void kernel_launch(void* const* d_in, const int* in_sizes, int n_in,
                              void* d_out, int out_size, void* d_ws, size_t ws_size,
                              hipStream_t stream)
{
    (void)in_sizes; (void)n_in; (void)out_size; (void)ws_size;
    const float* pts   = (const float*)d_in[0];
    const float* mpts  = (const float*)d_in[2];
    const float* mdesc = (const float*)d_in[3];
    const int*   usage = (const int*)d_in[4];
    float* out = (float*)d_out;

    char* ws = (char*)d_ws;
    float*    partKey = (float*)(ws + WS_PARTKEY);
    int*      partIdx = (int*)(ws + WS_PARTIDX);
    int*      hist    = (int*)(ws + WS_HIST);
    int*      Vp      = (int*)(ws + WS_V);
    int*      cnt     = (int*)(ws + WS_CNT);
    unsigned* keys    = (unsigned*)(ws + WS_KEYS);

    k_zero<<<1, 1024, 0, stream>>>(hist, cnt);
    dim3 gA(M_Q / QB, NSPLIT);
    k_argmin<<<gA, ABLK, 0, stream>>>(pts, mpts, partKey, partIdx);
    k_hist<<<64, 1024, 0, stream>>>(usage, hist);
    k_scanV<<<1, 1024, 0, stream>>>(hist, Vp);
    k_collect<<<512, 256, 0, stream>>>(usage, Vp, cnt, keys);
    k_copy<<<2048, 256, 0, stream>>>(mpts, mdesc, usage, out);
    k_final<<<1, 1024, 0, stream>>>(pts, partKey, partIdx, cnt, keys, out);
}

// Round 3
// 347.017 us; speedup vs baseline: 1.7897x; 1.2596x over previous
//
#include <hip/hip_runtime.h>

#define N_TOT   500000
#define M_Q     1024
#define QB      16
#define NSPLIT  16
#define CAND_MAX 8192

#define COPY_BLKS   2048
#define ARGMIN_BLKS 1024   // 64 query-tiles x 16 N-splits
#define HIST_BLKS   32
#define MEGA_BLKS   (COPY_BLKS + ARGMIN_BLKS + HIST_BLKS)
#define HIST_CHUNK  (N_TOT / HIST_BLKS)   // 15625

static const unsigned OUT_ROWS  = 259u * (unsigned)N_TOT;     // 129,500,000
static const unsigned OUT_USAGE = OUT_ROWS;
static const unsigned OUT_IDX   = OUT_ROWS + (unsigned)N_TOT; // 130,000,000

// ---- ws layout (bytes) ----
#define WS_PARTKEY 0                 // M*NSPLIT f32 = 65536
#define WS_PARTIDX 65536             // M*NSPLIT i32 = 65536
#define WS_HISTP   131072            // 32*1024 i32  = 131072 (plain stores, no zero needed)
#define WS_V       262144            // 1 i32
#define WS_CNT     262148            // 1 i32
#define WS_KEYS    262152            // CAND_MAX u32 = 32768

// =====================  MEGA: copy || argmin || hist-partials  =====================
__global__ __launch_bounds__(256) void k_mega(
    const float* __restrict__ pts,  const float* __restrict__ mpts,
    const float* __restrict__ mdesc, const int* __restrict__ usage,
    float* __restrict__ out,
    float* __restrict__ partKey, int* __restrict__ partIdx,
    int* __restrict__ histPart)
{
    __shared__ int smem[1024];
    const int b   = blockIdx.x;
    const int tid = threadIdx.x;

    if (b < COPY_BLKS) {
        // ---------------- copy role: rows + usage-as-float ----------------
        const unsigned TOTQ = (OUT_ROWS + (unsigned)N_TOT) / 4u;  // 32,500,000 float4
        const unsigned stride = COPY_BLKS * 256u;
        for (unsigned g = (unsigned)b * 256u + tid; g < TOTQ; g += stride) {
            unsigned e = g * 4u;
            float4 v;
            if (e < OUT_ROWS) {
                unsigned n = e / 259u;
                unsigned r = e - n * 259u;
                float tmp[4];
#pragma unroll
                for (int j = 0; j < 4; j++) {
                    tmp[j] = (r < 3u) ? mpts[n * 3u + r] : mdesc[n * 256u + (r - 3u)];
                    r++;
                    if (r == 259u) { r = 0u; n++; }
                }
                v = make_float4(tmp[0], tmp[1], tmp[2], tmp[3]);
            } else {
                unsigned n = e - OUT_ROWS;
                int4 u4 = *reinterpret_cast<const int4*>(usage + n);
                v = make_float4((float)u4.x, (float)u4.y, (float)u4.z, (float)u4.w);
            }
            *reinterpret_cast<float4*>(out + e) = v;
        }
    } else if (b < COPY_BLKS + ARGMIN_BLKS) {
        // ---------------- argmin role (math identical to R1/R2: absmax 0) -------------
        const int rb = b - COPY_BLKS;
        const int qb = rb & 63;
        const int ns = rb >> 6;
        const int qbase = qb * QB;
        const int chunk = N_TOT / NSPLIT;   // 31250
        const int n0 = ns * chunk;
        const int n1 = n0 + chunk;

        float* qs = (float*)smem;               // 48 floats
        float* wk = (float*)smem + 64;          // [4][16]
        int*   wi = smem + 192;                 // [4][16]
        if (tid < QB * 3) qs[tid] = pts[qbase * 3 + tid];
        __syncthreads();

        float qx[QB], qy[QB], qz[QB];
#pragma unroll
        for (int i = 0; i < QB; i++) { qx[i] = qs[3*i]; qy[i] = qs[3*i+1]; qz[i] = qs[3*i+2]; }

        float bk[QB]; int bi[QB];
#pragma unroll
        for (int i = 0; i < QB; i++) { bk[i] = INFINITY; bi[i] = 0x7fffffff; }

        for (int n = n0 + tid; n < n1; n += 256) {
            float x = mpts[3*n+0], y = mpts[3*n+1], z = mpts[3*n+2];
            float h = 0.5f * (x*x + y*y + z*z);
#pragma unroll
            for (int i = 0; i < QB; i++) {
                float key = h - x*qx[i] - y*qy[i] - z*qz[i];
                bool lt = key < bk[i];          // strict < + ascending n => first-min kept
                bk[i] = lt ? key : bk[i];
                bi[i] = lt ? n   : bi[i];
            }
        }

        const int lane = tid & 63;
        const int wv   = tid >> 6;
#pragma unroll
        for (int off = 32; off > 0; off >>= 1) {
#pragma unroll
            for (int i = 0; i < QB; i++) {
                float ok = __shfl_down(bk[i], off, 64);
                int   oi = __shfl_down(bi[i], off, 64);
                if (ok < bk[i] || (ok == bk[i] && oi < bi[i])) { bk[i] = ok; bi[i] = oi; }
            }
        }
        if (lane == 0) {
#pragma unroll
            for (int i = 0; i < QB; i++) { wk[wv*QB + i] = bk[i]; wi[wv*QB + i] = bi[i]; }
        }
        __syncthreads();
        if (tid < QB) {
            float k = wk[tid]; int ix = wi[tid];
#pragma unroll
            for (int w = 1; w < 4; w++) {
                float ok = wk[w*QB + tid]; int oi = wi[w*QB + tid];
                if (ok < k || (ok == k && oi < ix)) { k = ok; ix = oi; }
            }
            partKey[(qbase + tid) * NSPLIT + ns] = k;
            partIdx[(qbase + tid) * NSPLIT + ns] = ix;
        }
    } else {
        // ---------------- hist role: per-block partial histogram (plain stores) -------
        const int hb = b - COPY_BLKS - ARGMIN_BLKS;
        const int r0 = hb * HIST_CHUNK;
        const int r1 = r0 + HIST_CHUNK;
#pragma unroll
        for (int i = 0; i < 4; i++) smem[tid + i * 256] = 0;
        __syncthreads();
        for (int n = r0 + tid; n < r1; n += 256) {
            unsigned v = (unsigned)usage[n];
            if (v > 1023u) v = 1023u;
            atomicAdd(&smem[v], 1);
        }
        __syncthreads();
#pragma unroll
        for (int i = 0; i < 4; i++) {
            int bin = tid + i * 256;
            histPart[hb * 1024 + bin] = smem[bin];
        }
    }
}

// =====================  scanV: total hist, scan, cutoff V, zero cnt  ===============
__global__ __launch_bounds__(1024) void k_scanV(
    const int* __restrict__ histPart, int* __restrict__ Vout, int* __restrict__ cnt)
{
    __shared__ int scan[1024];
    const int t = threadIdx.x;
    int h = 0;
#pragma unroll
    for (int b = 0; b < HIST_BLKS; b++) h += histPart[b * 1024 + t];
    scan[t] = h; __syncthreads();
    for (int off = 1; off < 1024; off <<= 1) {
        int add = (t >= off) ? scan[t - off] : 0;
        __syncthreads();
        scan[t] += add;
        __syncthreads();
    }
    int cum  = scan[t] - h;    // count(usage < t)
    int cumN = scan[t];        // count(usage <= t)
    if (cum < M_Q && cumN >= M_Q) { *Vout = t; *cnt = 0; }
}

// =====================  collect candidates (usage <= V), unordered  ================
__global__ __launch_bounds__(256) void k_collect(
    const int* __restrict__ usage, const int* __restrict__ Vp,
    int* __restrict__ cnt, unsigned* __restrict__ keys)
{
    const int V = *Vp;
    const int stride = gridDim.x * 256;
    for (int n = blockIdx.x * 256 + threadIdx.x; n < N_TOT; n += stride) {
        int u = usage[n];
        if (u <= V) {
            int p = atomicAdd(cnt, 1);
            if (p < CAND_MAX) keys[p] = ((unsigned)u << 19) | (unsigned)n;
        }
    }
}

// =====================  final: sort, rank, idx out, usage bump  ====================
__global__ __launch_bounds__(1024) void k_final(
    const float* __restrict__ pts,
    const float* __restrict__ partKey, const int* __restrict__ partIdx,
    const int* __restrict__ cntP, const unsigned* __restrict__ keysG,
    float* __restrict__ out)
{
    __shared__ unsigned keys[CAND_MAX];
    __shared__ int      mscan[1024];
    const int t = threadIdx.x;

    // 1) reduce NSPLIT partials (ascending-n chunk order: strict <)
    float bk = INFINITY; int bi = 0x7fffffff;
#pragma unroll
    for (int s = 0; s < NSPLIT; s++) {
        float k = partKey[t * NSPLIT + s];
        int   i = partIdx[t * NSPLIT + s];
        if (k < bk) { bk = k; bi = i; }
    }
    float px = pts[3*t], py = pts[3*t+1], pz = pts[3*t+2];
    float d2 = px*px + py*py + pz*pz + 2.0f * bk;
    const bool mask = d2 > 1e-6f;   // sqrt(max(d2,1e-12)) > 1e-3

    // 2) load candidates, pad to next pow2 (C >= M_Q by construction of V)
    int C = *cntP; if (C > CAND_MAX) C = CAND_MAX;
    int P2 = 1; while (P2 < C) P2 <<= 1;
    for (int p = t; p < P2; p += 1024) keys[p] = (p < C) ? keysG[p] : 0xFFFFFFFFu;
    __syncthreads();

    // 3) bitonic sort ascending -> (usage asc, index asc) == lax.top_k order
    for (int k = 2; k <= P2; k <<= 1) {
        for (int j = k >> 1; j > 0; j >>= 1) {
            for (int i = t; i < P2; i += 1024) {
                int ixj = i ^ j;
                if (ixj > i) {
                    unsigned a = keys[i], b = keys[ixj];
                    bool up = ((i & k) == 0);
                    if ((a > b) == up) { keys[i] = b; keys[ixj] = a; }
                }
            }
            __syncthreads();
        }
    }

    // 4) rank = cumsum(mask)-1 ; final idx; outputs
    mscan[t] = mask ? 1 : 0; __syncthreads();
    for (int off = 1; off < 1024; off <<= 1) {
        int add = (t >= off) ? mscan[t - off] : 0;
        __syncthreads();
        mscan[t] += add;
        __syncthreads();
    }
    int rank = mscan[t] - 1;
    int idx = mask ? (int)(keys[rank] & 0x7FFFFu) : bi;
    out[(size_t)OUT_IDX + (size_t)t] = (float)idx;
    atomicAdd(out + OUT_USAGE + idx, 1.0f);   // after mega wrote base usage
}

extern "C" void kernel_launch(void* const* d_in, const int* in_sizes, int n_in,
                              void* d_out, int out_size, void* d_ws, size_t ws_size,
                              hipStream_t stream)
{
    (void)in_sizes; (void)n_in; (void)out_size; (void)ws_size;
    const float* pts   = (const float*)d_in[0];
    const float* mpts  = (const float*)d_in[2];
    const float* mdesc = (const float*)d_in[3];
    const int*   usage = (const int*)d_in[4];
    float* out = (float*)d_out;

    char* ws = (char*)d_ws;
    float*    partKey  = (float*)(ws + WS_PARTKEY);
    int*      partIdx  = (int*)(ws + WS_PARTIDX);
    int*      histPart = (int*)(ws + WS_HISTP);
    int*      Vp       = (int*)(ws + WS_V);
    int*      cnt      = (int*)(ws + WS_CNT);
    unsigned* keys     = (unsigned*)(ws + WS_KEYS);

    k_mega<<<MEGA_BLKS, 256, 0, stream>>>(pts, mpts, mdesc, usage, out,
                                          partKey, partIdx, histPart);
    k_scanV<<<1, 1024, 0, stream>>>(histPart, Vp, cnt);
    k_collect<<<64, 256, 0, stream>>>(usage, Vp, cnt, keys);
    k_final<<<1, 1024, 0, stream>>>(pts, partKey, partIdx, cnt, keys, out);
}

// Round 4
// 331.709 us; speedup vs baseline: 1.8723x; 1.0461x over previous
//
#include <hip/hip_runtime.h>

#define N_TOT   500000
#define M_Q     1024
#define QB      16
#define NSPLIT  16
#define CAND_MAX 8192

#define ARGMIN_BLKS 1024            // 64 query-tiles x 16 N-splits
#define HIST_BLKS   32
#define USAGE_BLKS  64
#define CROWS       16              // rows per copy block
#define COPY_BLKS   (N_TOT / CROWS) // 31250
#define MEGA_BLKS   (ARGMIN_BLKS + HIST_BLKS + USAGE_BLKS + COPY_BLKS)
#define HIST_CHUNK  (N_TOT / HIST_BLKS)   // 15625

static const unsigned OUT_ROWS  = 259u * (unsigned)N_TOT;     // 129,500,000
static const unsigned OUT_USAGE = OUT_ROWS;
static const unsigned OUT_IDX   = OUT_ROWS + (unsigned)N_TOT; // 130,000,000

// ---- ws layout (bytes) ----
#define WS_PARTKEY 0                 // M*NSPLIT f32 = 65536
#define WS_PARTIDX 65536             // M*NSPLIT i32 = 65536
#define WS_HISTP   131072            // 32*1024 i32  = 131072 (plain stores, no zeroing)
#define WS_V       262144            // 1 i32
#define WS_CNT     262148            // 1 i32
#define WS_KEYS    262152            // CAND_MAX u32 = 32768

// =====================  MEGA: argmin || hist || usage-copy || row-copy ==============
__global__ __launch_bounds__(256) void k_mega(
    const float* __restrict__ pts,  const float* __restrict__ mpts,
    const float* __restrict__ mdesc, const int* __restrict__ usage,
    float* __restrict__ out,
    float* __restrict__ partKey, int* __restrict__ partIdx,
    int* __restrict__ histPart)
{
    __shared__ float smem[CROWS * 259];   // 16576 B, unioned across roles
    const int b   = blockIdx.x;
    const int tid = threadIdx.x;

    if (b < ARGMIN_BLKS) {
        // ---------------- argmin role (math identical since R1: absmax 0) ----------
        const int qb = b & 63;
        const int ns = b >> 6;
        const int qbase = qb * QB;
        const int chunk = N_TOT / NSPLIT;   // 31250
        const int n0 = ns * chunk;
        const int n1 = n0 + chunk;

        float* qs = smem;                   // 48 floats
        float* wk = smem + 64;              // [4][16]
        int*   wi = (int*)(smem + 192);     // [4][16]
        if (tid < QB * 3) qs[tid] = pts[qbase * 3 + tid];
        __syncthreads();

        float qx[QB], qy[QB], qz[QB];
#pragma unroll
        for (int i = 0; i < QB; i++) { qx[i] = qs[3*i]; qy[i] = qs[3*i+1]; qz[i] = qs[3*i+2]; }

        float bk[QB]; int bi[QB];
#pragma unroll
        for (int i = 0; i < QB; i++) { bk[i] = INFINITY; bi[i] = 0x7fffffff; }

        for (int n = n0 + tid; n < n1; n += 256) {
            float x = mpts[3*n+0], y = mpts[3*n+1], z = mpts[3*n+2];
            float h = 0.5f * (x*x + y*y + z*z);
#pragma unroll
            for (int i = 0; i < QB; i++) {
                float key = h - x*qx[i] - y*qy[i] - z*qz[i];
                bool lt = key < bk[i];      // strict < + ascending n => first-min kept
                bk[i] = lt ? key : bk[i];
                bi[i] = lt ? n   : bi[i];
            }
        }

        const int lane = tid & 63;
        const int wv   = tid >> 6;
#pragma unroll
        for (int off = 32; off > 0; off >>= 1) {
#pragma unroll
            for (int i = 0; i < QB; i++) {
                float ok = __shfl_down(bk[i], off, 64);
                int   oi = __shfl_down(bi[i], off, 64);
                if (ok < bk[i] || (ok == bk[i] && oi < bi[i])) { bk[i] = ok; bi[i] = oi; }
            }
        }
        if (lane == 0) {
#pragma unroll
            for (int i = 0; i < QB; i++) { wk[wv*QB + i] = bk[i]; wi[wv*QB + i] = bi[i]; }
        }
        __syncthreads();
        if (tid < QB) {
            float k = wk[tid]; int ix = wi[tid];
#pragma unroll
            for (int w = 1; w < 4; w++) {
                float ok = wk[w*QB + tid]; int oi = wi[w*QB + tid];
                if (ok < k || (ok == k && oi < ix)) { k = ok; ix = oi; }
            }
            partKey[(qbase + tid) * NSPLIT + ns] = k;
            partIdx[(qbase + tid) * NSPLIT + ns] = ix;
        }
    } else if (b < ARGMIN_BLKS + HIST_BLKS) {
        // ---------------- hist role: per-block partial histogram -------------------
        const int hb = b - ARGMIN_BLKS;
        const int r0 = hb * HIST_CHUNK;
        const int r1 = r0 + HIST_CHUNK;
        int* lh = (int*)smem;
#pragma unroll
        for (int i = 0; i < 4; i++) lh[tid + i * 256] = 0;
        __syncthreads();
        for (int n = r0 + tid; n < r1; n += 256) {
            unsigned v = (unsigned)usage[n];
            if (v > 1023u) v = 1023u;
            atomicAdd(&lh[v], 1);
        }
        __syncthreads();
#pragma unroll
        for (int i = 0; i < 4; i++) {
            int bin = tid + i * 256;
            histPart[hb * 1024 + bin] = lh[bin];
        }
    } else if (b < ARGMIN_BLKS + HIST_BLKS + USAGE_BLKS) {
        // ---------------- usage-as-float role (int4 -> float4) ---------------------
        const int ub = b - ARGMIN_BLKS - HIST_BLKS;
        const int4* u4 = (const int4*)usage;
        float4* o4 = (float4*)(out + OUT_USAGE);        // 129.5e6 % 4 == 0: aligned
        const int TOT4 = N_TOT / 4;                     // 125000
        for (int g = ub * 256 + tid; g < TOT4; g += USAGE_BLKS * 256) {
            int4 u = u4[g];
            o4[g] = make_float4((float)u.x, (float)u.y, (float)u.z, (float)u.w);
        }
    } else {
        // ---------------- row-copy role: LDS-staged, both streams dwordx4 ----------
        const int cb = b - (ARGMIN_BLKS + HIST_BLKS + USAGE_BLKS);  // 0..31249
        const int n0 = cb * CROWS;
        // stage mdesc rows as the output image [CROWS][259] (cols 3..258)
        const float4* src = (const float4*)(mdesc + (size_t)n0 * 256);
#pragma unroll
        for (int it = 0; it < 4; it++) {
            int g = tid + it * 256;        // 0..1023 float4s
            float4 v = src[g];
            int e = g * 4;
            int r = e >> 8;
            int c = e & 255;
            float* d = smem + r * 259 + 3 + c;
            d[0] = v.x; d[1] = v.y; d[2] = v.z; d[3] = v.w;
        }
        // stage mpts (cols 0..2)
        if (tid < CROWS * 3) {
            int r = tid / 3, c = tid - r * 3;
            smem[r * 259 + c] = mpts[(size_t)n0 * 3 + tid];
        }
        __syncthreads();
        // store contiguous block span: 1036 aligned float4s
        float4* dst4 = (float4*)(out + (size_t)cb * (CROWS * 259));
        const float4* s4 = (const float4*)smem;
#pragma unroll
        for (int it = 0; it < 5; it++) {
            int g = tid + it * 256;
            if (g < CROWS * 259 / 4) dst4[g] = s4[g];
        }
    }
}

// =====================  scanV: total hist, scan, cutoff V, zero cnt  ===============
__global__ __launch_bounds__(1024) void k_scanV(
    const int* __restrict__ histPart, int* __restrict__ Vout, int* __restrict__ cnt)
{
    __shared__ int scan[1024];
    const int t = threadIdx.x;
    int h = 0;
#pragma unroll
    for (int b = 0; b < HIST_BLKS; b++) h += histPart[b * 1024 + t];
    scan[t] = h; __syncthreads();
    for (int off = 1; off < 1024; off <<= 1) {
        int add = (t >= off) ? scan[t - off] : 0;
        __syncthreads();
        scan[t] += add;
        __syncthreads();
    }
    int cum  = scan[t] - h;    // count(usage < t)
    int cumN = scan[t];        // count(usage <= t)
    if (cum < M_Q && cumN >= M_Q) { *Vout = t; *cnt = 0; }
}

// =====================  collect candidates (usage <= V), unordered  ================
__global__ __launch_bounds__(256) void k_collect(
    const int* __restrict__ usage, const int* __restrict__ Vp,
    int* __restrict__ cnt, unsigned* __restrict__ keys)
{
    const int V = *Vp;
    const int stride = gridDim.x * 256;
    for (int n = blockIdx.x * 256 + threadIdx.x; n < N_TOT; n += stride) {
        int u = usage[n];
        if (u <= V) {
            int p = atomicAdd(cnt, 1);
            if (p < CAND_MAX) keys[p] = ((unsigned)u << 19) | (unsigned)n;
        }
    }
}

// =====================  final: sort, rank, idx out, usage bump  ====================
__global__ __launch_bounds__(1024) void k_final(
    const float* __restrict__ pts,
    const float* __restrict__ partKey, const int* __restrict__ partIdx,
    const int* __restrict__ cntP, const unsigned* __restrict__ keysG,
    float* __restrict__ out)
{
    __shared__ unsigned keys[CAND_MAX];
    __shared__ int      mscan[1024];
    const int t = threadIdx.x;

    // 1) reduce NSPLIT partials (ascending-n chunk order: strict <)
    float bk = INFINITY; int bi = 0x7fffffff;
#pragma unroll
    for (int s = 0; s < NSPLIT; s++) {
        float k = partKey[t * NSPLIT + s];
        int   i = partIdx[t * NSPLIT + s];
        if (k < bk) { bk = k; bi = i; }
    }
    float px = pts[3*t], py = pts[3*t+1], pz = pts[3*t+2];
    float d2 = px*px + py*py + pz*pz + 2.0f * bk;
    const bool mask = d2 > 1e-6f;   // sqrt(max(d2,1e-12)) > 1e-3

    // 2) load candidates, pad to next pow2 (C >= M_Q by construction of V)
    int C = *cntP; if (C > CAND_MAX) C = CAND_MAX;
    int P2 = 1; while (P2 < C) P2 <<= 1;
    for (int p = t; p < P2; p += 1024) keys[p] = (p < C) ? keysG[p] : 0xFFFFFFFFu;
    __syncthreads();

    // 3) bitonic sort ascending -> (usage asc, index asc) == lax.top_k order
    for (int k = 2; k <= P2; k <<= 1) {
        for (int j = k >> 1; j > 0; j >>= 1) {
            for (int i = t; i < P2; i += 1024) {
                int ixj = i ^ j;
                if (ixj > i) {
                    unsigned a = keys[i], bb = keys[ixj];
                    bool up = ((i & k) == 0);
                    if ((a > bb) == up) { keys[i] = bb; keys[ixj] = a; }
                }
            }
            __syncthreads();
        }
    }

    // 4) rank = cumsum(mask)-1 ; final idx; outputs
    mscan[t] = mask ? 1 : 0; __syncthreads();
    for (int off = 1; off < 1024; off <<= 1) {
        int add = (t >= off) ? mscan[t - off] : 0;
        __syncthreads();
        mscan[t] += add;
        __syncthreads();
    }
    int rank = mscan[t] - 1;
    int idx = mask ? (int)(keys[rank] & 0x7FFFFu) : bi;
    out[(size_t)OUT_IDX + (size_t)t] = (float)idx;
    atomicAdd(out + OUT_USAGE + idx, 1.0f);   // after mega wrote base usage
}

extern "C" void kernel_launch(void* const* d_in, const int* in_sizes, int n_in,
                              void* d_out, int out_size, void* d_ws, size_t ws_size,
                              hipStream_t stream)
{
    (void)in_sizes; (void)n_in; (void)out_size; (void)ws_size;
    const float* pts   = (const float*)d_in[0];
    const float* mpts  = (const float*)d_in[2];
    const float* mdesc = (const float*)d_in[3];
    const int*   usage = (const int*)d_in[4];
    float* out = (float*)d_out;

    char* ws = (char*)d_ws;
    float*    partKey  = (float*)(ws + WS_PARTKEY);
    int*      partIdx  = (int*)(ws + WS_PARTIDX);
    int*      histPart = (int*)(ws + WS_HISTP);
    int*      Vp       = (int*)(ws + WS_V);
    int*      cnt      = (int*)(ws + WS_CNT);
    unsigned* keys     = (unsigned*)(ws + WS_KEYS);

    k_mega<<<MEGA_BLKS, 256, 0, stream>>>(pts, mpts, mdesc, usage, out,
                                          partKey, partIdx, histPart);
    k_scanV<<<1, 1024, 0, stream>>>(histPart, Vp, cnt);
    k_collect<<<64, 256, 0, stream>>>(usage, Vp, cnt, keys);
    k_final<<<1, 1024, 0, stream>>>(pts, partKey, partIdx, cnt, keys, out);
}